// Round 6
// baseline (93.900 us; speedup 1.0000x reference)
//
#include <hip/hip_runtime.h>

// ProteinMapper: torsion angles -> rigid frames -> atom positions
// B=64, L=2048, 21 restypes, 8 groups, 14 atoms.
//
// Round 6: counters showed WRITE_SIZE 70.5 MB vs 22 MB ideal (3.2x write
// amplification from 8B stores scattered at 168B lane stride). Fix: stage each
// block's output (256 residues x 42 f = 43008 B contiguous) in LDS, then store
// coalesced float4s. Tables stay transposed [element][aa] (bank-conflict-free).

constexpr int NRES_TOTAL = 64 * 2048;     // 131072 residues
constexpr int NRT = 21;                   // restypes
constexpr int NG  = 8;                    // groups
constexpr int NA  = 14;                   // atoms
constexpr int OUT_F = NA * 3;             // 42 floats per residue
constexpr int BLK = 256;
constexpr int OUT_F4 = BLK * OUT_F / 4;   // 2688 float4 per block

__global__ __launch_bounds__(256) void protein_mapper_kernel(
    const float* __restrict__ bb_rots,        // (B,L,3,3)
    const float* __restrict__ bb_trans,       // (B,L,3)
    const float* __restrict__ angles,         // (B,L,7,2)
    const int*   __restrict__ aatype,         // (B,L)
    const float* __restrict__ default_frames, // (21,8,4,4)
    const int*   __restrict__ group_idx,      // (21,14)
    const float* __restrict__ atom_mask,      // (21,14)
    const float* __restrict__ lit_positions,  // (21,14,3)
    float* __restrict__ out)                  // (B,L,14,3)
{
    // ---- LDS: transposed tables + output staging buffer ----
    __shared__ float s_frames[128 * NRT];     // [g*16+r*4+c][aa]   10752 B
    __shared__ int   s_gidx[NA * NRT];        // [a][aa]             1176 B
    __shared__ float s_mask[NA * NRT];        // [a][aa]             1176 B
    __shared__ float s_lit[NA * 3 * NRT];     // [a*3+c][aa]         3528 B
    __shared__ float s_out[BLK * OUT_F];      // per-thread stride 42, 43008 B

    for (int n = threadIdx.x; n < NRT * 128; n += BLK) {
        const int aa = n / 128, j = n % 128;
        s_frames[j * NRT + aa] = default_frames[n];
    }
    for (int n = threadIdx.x; n < NRT * NA; n += BLK) {
        const int aa = n / NA, a = n % NA;
        s_gidx[a * NRT + aa] = group_idx[n];
        s_mask[a * NRT + aa] = atom_mask[n];
    }
    for (int n = threadIdx.x; n < NRT * NA * 3; n += BLK) {
        const int aa = n / (NA * 3), k = n % (NA * 3);
        s_lit[k * NRT + aa] = lit_positions[n];
    }
    __syncthreads();

    // grid is exactly NRES_TOTAL threads (512 x 256); no OOB guard needed
    const int i = blockIdx.x * BLK + threadIdx.x;
    const int aa = aatype[i];

    // ---- sin/cos per group (group 0 = backbone identity [s=0,c=1]) ----
    float sv[NG], cv[NG];
    sv[0] = 0.0f; cv[0] = 1.0f;
    const float2* angp = reinterpret_cast<const float2*>(angles + (size_t)i * 14);
    #pragma unroll
    for (int g = 1; g < NG; ++g) {
        float2 sc = angp[g - 1];
        sv[g] = sc.x;
        cv[g] = sc.y;
    }

    // ---- build local frames: G[g][0..8] = dR @ rotx(s,c), G[g][9..11] = dt ----
    float G[NG][12];
    #pragma unroll
    for (int g = 0; g < NG; ++g) {
        const float cg = cv[g], sg = sv[g];
        #pragma unroll
        for (int r = 0; r < 3; ++r) {
            const float a0 = s_frames[(g * 16 + r * 4 + 0) * NRT + aa];
            const float a1 = s_frames[(g * 16 + r * 4 + 1) * NRT + aa];
            const float a2 = s_frames[(g * 16 + r * 4 + 2) * NRT + aa];
            const float a3 = s_frames[(g * 16 + r * 4 + 3) * NRT + aa];
            G[g][r * 3 + 0] = a0;
            G[g][r * 3 + 1] = cg * a1 + sg * a2;
            G[g][r * 3 + 2] = cg * a2 - sg * a1;
            G[g][9 + r]     = a3;
        }
    }

    // ---- compose chain for groups 5,6,7: G[g] <- G[g-1] ∘ G[g] ----
    #pragma unroll
    for (int g = 5; g < NG; ++g) {
        float Q[12];
        #pragma unroll
        for (int r = 0; r < 3; ++r) {
            const float p0 = G[g - 1][r * 3 + 0];
            const float p1 = G[g - 1][r * 3 + 1];
            const float p2 = G[g - 1][r * 3 + 2];
            #pragma unroll
            for (int cdx = 0; cdx < 3; ++cdx)
                Q[r * 3 + cdx] = p0 * G[g][cdx] + p1 * G[g][3 + cdx] + p2 * G[g][6 + cdx];
            Q[9 + r] = p0 * G[g][9] + p1 * G[g][10] + p2 * G[g][11] + G[g - 1][9 + r];
        }
        #pragma unroll
        for (int k = 0; k < 12; ++k) G[g][k] = Q[k];
    }

    // ---- backbone frame ----
    const float* br = bb_rots + (size_t)i * 9;
    const float b00 = br[0], b01 = br[1], b02 = br[2];
    const float b10 = br[3], b11 = br[4], b12 = br[5];
    const float b20 = br[6], b21 = br[7], b22 = br[8];
    const float* btp = bb_trans + (size_t)i * 3;
    const float bt0 = btp[0], bt1 = btp[1], bt2 = btp[2];

    // ---- per-atom: 3-level cndmask tree selects G[ga]; results -> LDS ----
    float* my = s_out + threadIdx.x * OUT_F;
    #pragma unroll
    for (int a = 0; a < NA; ++a) {
        const int   ga = s_gidx[a * NRT + aa];
        const float m_ = s_mask[a * NRT + aa];
        const float lx = s_lit[(a * 3 + 0) * NRT + aa];
        const float ly = s_lit[(a * 3 + 1) * NRT + aa];
        const float lz = s_lit[(a * 3 + 2) * NRT + aa];
        const bool b0_ = ga & 1, b1_ = ga & 2, b2_ = ga & 4;
        float S[12];
        #pragma unroll
        for (int e = 0; e < 12; ++e) {
            const float t0 = b0_ ? G[1][e] : G[0][e];
            const float t1 = b0_ ? G[3][e] : G[2][e];
            const float t2 = b0_ ? G[5][e] : G[4][e];
            const float t3 = b0_ ? G[7][e] : G[6][e];
            const float u0 = b1_ ? t1 : t0;
            const float u1 = b1_ ? t3 : t2;
            S[e] = b2_ ? u1 : u0;
        }
        const float px = S[0] * lx + S[1] * ly + S[2] * lz + S[9];
        const float py = S[3] * lx + S[4] * ly + S[5] * lz + S[10];
        const float pz = S[6] * lx + S[7] * ly + S[8] * lz + S[11];
        my[a * 3 + 0] = (b00 * px + b01 * py + b02 * pz + bt0) * m_;
        my[a * 3 + 1] = (b10 * px + b11 * py + b12 * pz + bt1) * m_;
        my[a * 3 + 2] = (b20 * px + b21 * py + b22 * pz + bt2) * m_;
    }
    __syncthreads();

    // ---- coalesced block output: contiguous 43008 B as float4 ----
    const float4* s4 = reinterpret_cast<const float4*>(s_out);
    float4* o4 = reinterpret_cast<float4*>(out + (size_t)blockIdx.x * (BLK * OUT_F));
    for (int j = threadIdx.x; j < OUT_F4; j += BLK)
        o4[j] = s4[j];
}

extern "C" void kernel_launch(void* const* d_in, const int* in_sizes, int n_in,
                              void* d_out, int out_size, void* d_ws, size_t ws_size,
                              hipStream_t stream) {
    const float* bb_rots        = (const float*)d_in[0];
    const float* bb_trans       = (const float*)d_in[1];
    const float* angles         = (const float*)d_in[2];
    const int*   aatype         = (const int*)d_in[3];
    const float* default_frames = (const float*)d_in[4];
    const int*   group_idx      = (const int*)d_in[5];
    const float* atom_mask      = (const float*)d_in[6];
    const float* lit_positions  = (const float*)d_in[7];
    float* out = (float*)d_out;

    const int blocks = NRES_TOTAL / BLK;   // 512, exact
    protein_mapper_kernel<<<blocks, BLK, 0, stream>>>(
        bb_rots, bb_trans, angles, aatype,
        default_frames, group_idx, atom_mask, lit_positions, out);
}